// Round 10
// baseline (3882.877 us; speedup 1.0000x reference)
//
#include <hip/hip_runtime.h>
#include <cstddef>
#include <cstdint>

#define BN_EPS 1e-5f

typedef _Float16 half8 __attribute__((ext_vector_type(8)));
typedef float f32x4v __attribute__((ext_vector_type(4)));

// pack fp32 (pre-scaled) into fp16 high/low split: v = h + l/2048
__device__ __forceinline__ unsigned split_pack(float v) {
    _Float16 h = (_Float16)v;
    float r = (v - (float)h) * 2048.0f;
    _Float16 l = (_Float16)r;
    unsigned short hu = __builtin_bit_cast(unsigned short, h);
    unsigned short lu = __builtin_bit_cast(unsigned short, l);
    return (unsigned)hu | ((unsigned)lu << 16);
}

// 8 packed (h|l) u32 -> uint4 of 8 h-halfs + uint4 of 8 l-halfs
__device__ __forceinline__ void splitHL(uint4 a, uint4 b2, uint4& h, uint4& l) {
    h.x = (a.x & 0xffffu) | (a.y << 16);
    h.y = (a.z & 0xffffu) | (a.w << 16);
    h.z = (b2.x & 0xffffu) | (b2.y << 16);
    h.w = (b2.z & 0xffffu) | (b2.w << 16);
    l.x = (a.x >> 16) | (a.y & 0xffff0000u);
    l.y = (a.z >> 16) | (a.w & 0xffff0000u);
    l.z = (b2.x >> 16) | (b2.y & 0xffff0000u);
    l.w = (b2.z >> 16) | (b2.w & 0xffff0000u);
}

// ===== prep: w[co][ci][kw] fp32 -> WH/WL [kw][co][CIPAD] u16 planes, x256
__global__ __launch_bounds__(256)
void prep_w(const float* __restrict__ w, unsigned short* __restrict__ wh,
            unsigned short* __restrict__ wl, int Cin, int KW, int CIPAD)
{
    int id = blockIdx.x * 256 + threadIdx.x;
    int total = KW * 768 * CIPAD;
    if (id >= total) return;
    int cip = id % CIPAD;
    int co  = (id / CIPAD) % 768;
    int kw  = id / (CIPAD * 768);
    float v = 0.0f;
    if (cip < Cin) v = w[((size_t)co * Cin + cip) * KW + kw];
    unsigned pk = split_pack(v * 256.0f);
    wh[id] = (unsigned short)pk;
    wl[id] = (unsigned short)(pk >> 16);
}

// ===== prep: mels[b][80][1024] fp32 -> MH/ML [b][1032][96] u16 planes, x16
__global__ __launch_bounds__(256)
void prep_mels(const float* __restrict__ mels, unsigned short* __restrict__ mh,
               unsigned short* __restrict__ ml)
{
    int id = blockIdx.x * 256 + threadIdx.x;
    if (id >= 32 * 1032 * 96) return;
    int c = id % 96;
    int t = (id / 96) % 1032;
    int b = id / (96 * 1032);
    float v = 0.0f;
    if (c < 80 && t < 1024) v = mels[((size_t)b * 80 + c) * 1024 + t];
    unsigned pk = split_pack(v * 16.0f);
    mh[id] = (unsigned short)pk;
    ml[id] = (unsigned short)(pk >> 16);
}

// ===== fp16x3-split MFMA conv + BN + ReLU =====================================
// R10: tile 64co x 128t (was 128x128). Motivation (counter evidence):
// conv3/4/5 at 768 blocks / 512 concurrent slots = 1.5 rounds -> 2nd round
// runs at HALF machine (~150 us idle). New grids: conv1/2 3072 blocks,
// conv3/4/5 1536 -> EXACT rounds at both 2/CU and 3/CU. LDS shrinks to
// 48KB -> 3 blocks/CU possible (24 waves/CU, 6/SIMD) if regs fit:
// acc 2x2 HL = 32 + arch ~55 -> launch_bounds(512,6).
// 8 waves: wave tile 32co x 32t (wm=(wv&1)*32, wn=(wv>>1)*32).
// Staging: waves 0-3 stage A (row=tid>>2, oct=tid&3: contiguous-1KB LDS
// writes, 64B/row global chunks); waves 4-7 stage B (R7 map).
// Per-buffer planes (halfs): AH 0, AL 2048, BH 4096, BL 8192; stride 12288.
// Same plane formulas, same MFMA order, numerics bit-identical to R9.
// Kept: R2 swizzle, R7 512-thr/one-operand staging, R8 pre-split H/L
// planes (zero staging VALU), R9 lgkm-only barrier (neutral, harmless).
// Reverted history: R1 gload_lds, R3 global-A, R4 kw-inner, R5 rotation,
// R6 write-remap.
// A = weights (x256), B = acts (x16); result=(accHH+accX/2048)/4096.
// C/D layout (m89): col=lane&15, row=quad*4+reg.
// EPI=0: H/L u16 planes [t][768] via packed bounce; EPI=1: fp32 [co][TOUT].
template<int KW, int S, int P, int CIPAD, int TIN, int TSIN, int TOUT, int TSOUT, int EPI>
__global__ __launch_bounds__(512, 6)
void conv_mfma(const unsigned short* __restrict__ XH, const unsigned short* __restrict__ XL,
               const unsigned short* __restrict__ WH, const unsigned short* __restrict__ WL,
               const float* __restrict__ gamma, const float* __restrict__ beta,
               const float* __restrict__ mean, const float* __restrict__ var,
               unsigned short* __restrict__ OutH, unsigned short* __restrict__ OutL,
               float* __restrict__ Fout)
{
    constexpr int NCI = CIPAD / 32;
    constexpr int NC  = KW * NCI;          // >= 9 for all convs
    __shared__ unsigned smem[12288];       // 49152 B: 2 buffers x 24KB; bounce [128][68]
    _Float16* sm = (_Float16*)smem;

    // --- XCD-aware bijective swizzle (cox fastest within an XCD chunk) ---
    const int gx = gridDim.x, gy = gridDim.y;
    const int nwg  = gx * gy * (int)gridDim.z;       // % 8 == 0 for all launches
    const int flat = blockIdx.x + gx * (blockIdx.y + gy * blockIdx.z);
    const int swz  = (flat & 7) * (nwg >> 3) + (flat >> 3);
    const int cox  = swz % gx;
    const int rem  = swz / gx;
    const int ty   = rem % gy;
    const int b    = rem / gy;

    const int co0 = cox * 64;
    const int t0  = ty * 128;
    const int tid = threadIdx.x;
    const int lane = tid & 63, wv = tid >> 6;        // wv 0..7
    const int quad = lane >> 4, l16 = lane & 15;
    const int wm = (wv & 1) * 32;                    // 2 M-groups of 32
    const int wn = (wv >> 1) * 32;                   // 4 N-groups of 32

    f32x4v accH[2][2] = {};
    f32x4v accX[2][2] = {};

    // staging: waves 0-3 -> A, waves 4-7 -> B
    const bool isA = tid < 256;
    const int arow = tid >> 2, aoct = tid & 3;       // A: 64 rows x 4 octets
    const int r2   = tid & 255;
    const int srow = r2 >> 1, sh = r2 & 1;           // B: 128 rows, octet pairs
    const unsigned short* __restrict__ xhb = XH + (size_t)b * TSIN * CIPAD;
    const unsigned short* __restrict__ xlb = XL + (size_t)b * TSIN * CIPAD;

    uint4 rH[2], rL[2];

    auto loadT = [&](int c) {
        const int kw  = c / NCI;           // kw-major (R2 order)
        const int ci0 = (c % NCI) * 32;
        if (isA) {
            const size_t o = (size_t)(kw * 768 + co0 + arow) * CIPAD + ci0 + aoct * 8;
            rH[0] = *(const uint4*)(WH + o);
            rL[0] = *(const uint4*)(WL + o);
        } else {
            const int tp = (t0 + srow) * S + kw - P;
            rH[0] = rH[1] = rL[0] = rL[1] = make_uint4(0, 0, 0, 0);
            if ((unsigned)tp < (unsigned)TIN) {
                const size_t o = (size_t)tp * CIPAD + ci0;
                rH[0] = *(const uint4*)(xhb + o + sh * 8);
                rH[1] = *(const uint4*)(xhb + o + (sh + 2) * 8);
                rL[0] = *(const uint4*)(xlb + o + sh * 8);
                rL[1] = *(const uint4*)(xlb + o + (sh + 2) * 8);
            }
        }
    };

    auto storeT = [&](int pbuf) {
        const int b0 = pbuf * 12288;
        if (isA) {
            const int u = ((arow >> 4) * 4 + aoct) * 128 + (arow & 15) * 8;
            *(uint4*)(sm + b0 + 0    + u) = rH[0];
            *(uint4*)(sm + b0 + 2048 + u) = rL[0];
        } else {
            const int u1 = ((srow >> 4) * 4 + sh) * 128 + (srow & 15) * 8;
            const int u2 = u1 + 256;       // octet sh+2
            *(uint4*)(sm + b0 + 4096 + u1) = rH[0];
            *(uint4*)(sm + b0 + 8192 + u1) = rL[0];
            *(uint4*)(sm + b0 + 4096 + u2) = rH[1];
            *(uint4*)(sm + b0 + 8192 + u2) = rL[1];
        }
    };

    // LDS-only barrier (R9): drains ds ops, leaves register prefetch in flight.
    auto ldsBarrier = [] {
        asm volatile("s_waitcnt lgkmcnt(0)" ::: "memory");
        __builtin_amdgcn_s_barrier();
        asm volatile("" ::: "memory");
    };

    loadT(0);
    storeT(0);
    if (NC > 1) loadT(1);
    ldsBarrier();

    int p = 0;
    for (int c = 0; c < NC; ++c) {
        const int base = p * 12288;
        if (c + 1 < NC) storeT(p ^ 1);     // drains reg set into other buffer
        if (c + 2 < NC) loadT(c + 2);      // refills reg set; in flight across barrier

        half8 bh[2], bl[2];
#pragma unroll
        for (int nt = 0; nt < 2; ++nt) {
            int gn = (wv >> 1) * 2 + nt;   // 0..7
            int u = (gn * 4 + quad) * 128 + l16 * 8;
            bh[nt] = *(const half8*)(sm + base + 4096 + u);
            bl[nt] = *(const half8*)(sm + base + 8192 + u);
        }
#pragma unroll
        for (int mt = 0; mt < 2; ++mt) {
            int gm = (wv & 1) * 2 + mt;    // 0..3
            int u = (gm * 4 + quad) * 128 + l16 * 8;
            half8 ah = *(const half8*)(sm + base + 0    + u);
            half8 al = *(const half8*)(sm + base + 2048 + u);
#pragma unroll
            for (int nt = 0; nt < 2; ++nt) {
                accH[mt][nt] = __builtin_amdgcn_mfma_f32_16x16x32_f16(ah, bh[nt], accH[mt][nt], 0, 0, 0);
                accX[mt][nt] = __builtin_amdgcn_mfma_f32_16x16x32_f16(ah, bl[nt], accX[mt][nt], 0, 0, 0);
                accX[mt][nt] = __builtin_amdgcn_mfma_f32_16x16x32_f16(al, bh[nt], accX[mt][nt], 0, 0, 0);
            }
        }
        ldsBarrier();                      // reads of p + ds_writes to p^1 drained
        p ^= 1;
    }

    if constexpr (EPI == 0) {
        unsigned* bb = smem;                       // bounce: [t_local 128][co_local 64 +4pad]
#pragma unroll
        for (int mt = 0; mt < 2; ++mt) {
#pragma unroll
            for (int r = 0; r < 4; ++r) {
                int mloc = wm + mt * 16 + quad * 4 + r;   // C/D row = co_local
                int co = co0 + mloc;
                float iv = gamma[co] / sqrtf(var[co] + BN_EPS);
                float sh2 = beta[co] - mean[co] * iv;
#pragma unroll
                for (int nt = 0; nt < 2; ++nt) {
                    float vf = (accH[mt][nt][r] + accX[mt][nt][r] * (1.0f / 2048.0f)) * (1.0f / 4096.0f);
                    float y = fmaf(vf, iv, sh2);
                    y = y > 0.0f ? y : 0.0f;
                    bb[(wn + nt * 16 + l16) * 68 + mloc] = split_pack(y * 16.0f);
                }
            }
        }
        __syncthreads();
        int tl = tid >> 2, seg = tid & 3;          // 128 rows x 4 segs of 16 co
        int t = t0 + tl;
        if (t < TOUT) {
            const uint4* src = (const uint4*)(bb + tl * 68 + seg * 16);
            size_t base2 = ((size_t)b * TSOUT + t) * 768 + co0 + seg * 16;   // half idx
#pragma unroll
            for (int i = 0; i < 2; ++i) {
                uint4 h, l;
                splitHL(src[2 * i], src[2 * i + 1], h, l);
                *(uint4*)(OutH + base2 + i * 8) = h;
                *(uint4*)(OutL + base2 + i * 8) = l;
            }
        }
    } else {
#pragma unroll
        for (int mt = 0; mt < 2; ++mt) {
#pragma unroll
            for (int r = 0; r < 4; ++r) {
                int co = co0 + wm + mt * 16 + quad * 4 + r;
                float iv = gamma[co] / sqrtf(var[co] + BN_EPS);
                float sh2 = beta[co] - mean[co] * iv;
                float* op = Fout + ((size_t)b * 768 + co) * TOUT;
#pragma unroll
                for (int nt = 0; nt < 2; ++nt) {
                    int t = t0 + wn + nt * 16 + l16;
                    if (t < TOUT) {
                        float vf = (accH[mt][nt][r] + accX[mt][nt][r] * (1.0f / 2048.0f)) * (1.0f / 4096.0f);
                        float y = fmaf(vf, iv, sh2);
                        op[t] = y > 0.0f ? y : 0.0f;
                    }
                }
            }
        }
    }
}

// ================= 1x1 conv (C=768 -> D=64) + bias, output z[b][t][d] =======
constexpr int TM = 64, TN = 64, TK = 16;

__global__ __launch_bounds__(256)
void conv1x1_bias_T(const float* __restrict__ in, const float* __restrict__ w,
                    const float* __restrict__ bias, float* __restrict__ z,
                    int Cin, int T)
{
    const int b   = blockIdx.z;
    const int t0  = blockIdx.y * TN;
    const int tid = threadIdx.x;

    __shared__ float As[TK][TM + 4];
    __shared__ float Bs[TK][TN + 4];

    float acc[4][4] = {};

    const int m0 = (tid & 15) * 4;
    const int n0 = (tid >> 4) * 4;

    const float* __restrict__ inb = in + (size_t)b * Cin * T;

    const int a_m = tid >> 4;
    const int a_k = tid & 15;
    const int b_k = tid >> 6;
    const int b_n = tid & 63;

    for (int kc = 0; kc < Cin; kc += TK) {
        __syncthreads();
#pragma unroll
        for (int i = 0; i < 4; ++i) {
            int m = a_m + 16 * i;
            As[a_k][m] = w[(size_t)m * Cin + kc + a_k];
        }
#pragma unroll
        for (int i = 0; i < 4; ++i) {
            int kk = b_k + 4 * i;
            int ci = kc + kk;
            int t  = t0 + b_n;
            Bs[kk][b_n] = (t < T) ? inb[(size_t)ci * T + t] : 0.0f;
        }
        __syncthreads();
#pragma unroll
        for (int kk = 0; kk < TK; ++kk) {
            float4 av = *reinterpret_cast<const float4*>(&As[kk][m0]);
            float4 bv = *reinterpret_cast<const float4*>(&Bs[kk][n0]);
            float am[4] = {av.x, av.y, av.z, av.w};
            float bn[4] = {bv.x, bv.y, bv.z, bv.w};
#pragma unroll
            for (int mi = 0; mi < 4; ++mi)
#pragma unroll
                for (int nj = 0; nj < 4; ++nj)
                    acc[mi][nj] = fmaf(am[mi], bn[nj], acc[mi][nj]);
        }
    }

    float4 bb = *reinterpret_cast<const float4*>(&bias[m0]);
    float bs[4] = {bb.x, bb.y, bb.z, bb.w};
#pragma unroll
    for (int nj = 0; nj < 4; ++nj) {
        int t = t0 + n0 + nj;
        if (t < T) {
            float4 v;
            v.x = acc[0][nj] + bs[0];
            v.y = acc[1][nj] + bs[1];
            v.z = acc[2][nj] + bs[2];
            v.w = acc[3][nj] + bs[3];
            *reinterpret_cast<float4*>(&z[((size_t)b * T + t) * 64 + m0]) = v;
        }
    }
}

// ============================== VQ kernels ==================================
__global__ __launch_bounds__(256)
void vq_e2(const float* __restrict__ emb, float* __restrict__ e2)
{
    int m = blockIdx.x * 256 + threadIdx.x;
    if (m < 512) {
        float s = 0.0f;
#pragma unroll
        for (int d = 0; d < 64; ++d) {
            float v = emb[(size_t)m * 64 + d];
            s = fmaf(v, v, s);
        }
        e2[m] = s;
    }
}

// R9 (kept): 256 thr (4 waves) per 64 points; codebook split across waves,
// lexicographic (dist, idx) merge == argmin-first semantics.
__global__ __launch_bounds__(256)
void vq_argmin(const float* __restrict__ z, const float* __restrict__ emb,
               const float* __restrict__ e2, int* __restrict__ idx,
               float* __restrict__ counts, int N)
{
    __shared__ float Es[256 * 64];        // 64KB
    __shared__ float bestS[4][64];
    __shared__ int   biS[4][64];
    const int tid = threadIdx.x;
    const int pt  = tid & 63;
    const int wvq = tid >> 6;             // wave 0..3
    const int n   = blockIdx.x * 64 + pt;
    const bool act = n < N;

    float x[64];
    float x2 = 0.0f;
    if (act) {
        const float4* zp = reinterpret_cast<const float4*>(z + (size_t)n * 64);
#pragma unroll
        for (int i = 0; i < 16; ++i) {
            float4 v = zp[i];
            x[4 * i + 0] = v.x; x[4 * i + 1] = v.y;
            x[4 * i + 2] = v.z; x[4 * i + 3] = v.w;
        }
#pragma unroll
        for (int d = 0; d < 64; ++d) x2 = fmaf(x[d], x[d], x2);
    }

    float best = 3.4e38f;
    int   bi   = 0;
    for (int pass = 0; pass < 2; ++pass) {
        __syncthreads();
        const float4* ep  = reinterpret_cast<const float4*>(emb + (size_t)pass * 16384);
        float4*       esp = reinterpret_cast<float4*>(Es);
#pragma unroll
        for (int i = 0; i < 16; ++i) esp[tid + 256 * i] = ep[tid + 256 * i];
        __syncthreads();
        const int c = pass * 4 + wvq;
        for (int r = 0; r < 64; ++r) {
            const float4* er = reinterpret_cast<const float4*>(&Es[((size_t)wvq * 64 + r) * 64]);
            float dot = 0.0f;
#pragma unroll
            for (int i = 0; i < 16; ++i) {
                float4 e4 = er[i];
                dot = fmaf(x[4 * i + 0], e4.x, dot);
                dot = fmaf(x[4 * i + 1], e4.y, dot);
                dot = fmaf(x[4 * i + 2], e4.z, dot);
                dot = fmaf(x[4 * i + 3], e4.w, dot);
            }
            float dist = (e2[c * 64 + r] + x2) - 2.0f * dot;  // reference op order
            if (dist < best) { best = dist; bi = c * 64 + r; }
        }
    }
    bestS[wvq][pt] = best;
    biS[wvq][pt]   = bi;
    __syncthreads();
    if (wvq == 0 && act) {
        float bd = bestS[0][pt];
        int   bx = biS[0][pt];
#pragma unroll
        for (int g = 1; g < 4; ++g) {
            float d = bestS[g][pt];
            int   i2 = biS[g][pt];
            if (d < bd || (d == bd && i2 < bx)) { bd = d; bx = i2; }
        }
        idx[n] = bx;
        atomicAdd(&counts[bx], 1.0f);
    }
}

__global__ __launch_bounds__(256)
void vq_quant_loss(const float* __restrict__ z, const float* __restrict__ emb,
                   const int* __restrict__ idx, float* __restrict__ qout,
                   double* __restrict__ loss_sum, int Ntot)
{
    int g = blockIdx.x * 256 + threadIdx.x;
    float d2 = 0.0f;
    if (g < Ntot) {
        int n = g >> 6;
        int d = g & 63;
        float q  = emb[(size_t)idx[n] * 64 + d];
        float zv = z[g];
        qout[g] = zv + (q - zv);
        float diff = zv - q;
        d2 = diff * diff;
    }
#pragma unroll
    for (int o = 32; o > 0; o >>= 1) d2 += __shfl_down(d2, o);
    __shared__ float wsum[4];
    if ((threadIdx.x & 63) == 0) wsum[threadIdx.x >> 6] = d2;
    __syncthreads();
    if (threadIdx.x == 0)
        atomicAdd(loss_sum, (double)(wsum[0] + wsum[1] + wsum[2] + wsum[3]));
}

__global__ __launch_bounds__(512)
void vq_finalize(const float* __restrict__ counts, const double* __restrict__ loss_sum,
                 float* __restrict__ out, int Ntot, int Npts)
{
    int t = threadIdx.x;
    float c   = counts[t];
    float avg = c / (float)Npts;
    float term = avg * logf(avg + 1e-10f);
#pragma unroll
    for (int o = 32; o > 0; o >>= 1) term += __shfl_down(term, o);
    __shared__ float wsum[8];
    if ((t & 63) == 0) wsum[t >> 6] = term;
    __syncthreads();
    if (t == 0) {
        float s = 0.0f;
        for (int i = 0; i < 8; ++i) s += wsum[i];
        out[Ntot]     = 0.25f * (float)(loss_sum[0] / (double)Ntot);
        out[Ntot + 1] = expf(-s);
    }
}

// ================================ launcher ==================================
extern "C" void kernel_launch(void* const* d_in, const int* in_sizes, int n_in,
                              void* d_out, int out_size, void* d_ws, size_t ws_size,
                              hipStream_t stream)
{
    const float* mels     = (const float*)d_in[0];
    const float* w1       = (const float*)d_in[1];
    const float* w2       = (const float*)d_in[2];
    const float* w3       = (const float*)d_in[3];
    const float* w4       = (const float*)d_in[4];
    const float* w5       = (const float*)d_in[5];
    const float* w6       = (const float*)d_in[6];
    const float* b6       = (const float*)d_in[7];
    const float* bn_gamma = (const float*)d_in[8];
    const float* bn_beta  = (const float*)d_in[9];
    const float* bn_mean  = (const float*)d_in[10];
    const float* bn_var   = (const float*)d_in[11];
    const float* emb      = (const float*)d_in[12];

    constexpr int B = 32, C = 768, D = 64, T2 = 511;

    // Activations as H/L u16 planes [b][1024][768] (50,331,648 B each).
    char* ws = (char*)d_ws;
    constexpr size_t ACT = (size_t)32 * 1024 * 768;            // halfs per plane
    unsigned short* P1H = (unsigned short*)ws;
    unsigned short* P1L = P1H + ACT;
    unsigned short* P2H = (unsigned short*)(ws + 100663296);
    unsigned short* P2L = P2H + ACT;
    unsigned short* WHp = (unsigned short*)(ws + 201326592);   // 4,718,592 B (max KW=4)
    unsigned short* WLp = WHp + (size_t)4 * 768 * 768;         // 4,718,592 B
    size_t misc  = 201326592 + 9437184;
    float*  counts = (float*)(ws + misc);              // 2048 B
    double* lossp  = (double*)(ws + misc + 2048);      // 8 B (+pad)
    float*  e2p    = (float*)(ws + misc + 2048 + 64);  // 2048 B
    int*    idx    = (int*)(ws + misc + 2048 + 64 + 2048);  // 65,408 B

    unsigned short* MH = P2H;                          // mels planes (dead before conv2 out)
    unsigned short* ML = P2L;
    float* bufA = (float*)ws;                          // conv5 fp32 out (P1 dead)
    float* z    = (float*)(ws + 100663296);            // conv6 out (P2 dead)

    hipMemsetAsync(ws + misc, 0, 2048 + 64, stream);   // counts + loss

    vq_e2<<<dim3(2), 256, 0, stream>>>(emb, e2p);
    prep_mels<<<dim3((32 * 1032 * 96 + 255) / 256), 256, 0, stream>>>(mels, MH, ML);

    // conv1: Cin 80 (pad 96), KW 3, S1 P0, in MH/ML[1032][96] -> x1 = P1 [1024][768]
    prep_w<<<dim3((3 * 768 * 96 + 255) / 256), 256, 0, stream>>>(w1, WHp, WLp, 80, 3, 96);
    conv_mfma<3, 1, 0, 96, 1032, 1032, 1022, 1024, 0><<<dim3(12, 8, B), 512, 0, stream>>>(
        MH, ML, WHp, WLp, bn_gamma + 0 * C, bn_beta + 0 * C, bn_mean + 0 * C, bn_var + 0 * C,
        P1H, P1L, nullptr);
    // conv2: x1(P1) -> x2(P2)
    prep_w<<<dim3((3 * 768 * 768 + 255) / 256), 256, 0, stream>>>(w2, WHp, WLp, 768, 3, 768);
    conv_mfma<3, 1, 1, 768, 1022, 1024, 1022, 1024, 0><<<dim3(12, 8, B), 512, 0, stream>>>(
        P1H, P1L, WHp, WLp, bn_gamma + 1 * C, bn_beta + 1 * C, bn_mean + 1 * C, bn_var + 1 * C,
        P2H, P2L, nullptr);
    // conv3: stride 2, KW 4: x2(P2) -> x3(P1, stride 512)
    prep_w<<<dim3((4 * 768 * 768 + 255) / 256), 256, 0, stream>>>(w3, WHp, WLp, 768, 4, 768);
    conv_mfma<4, 2, 1, 768, 1022, 1024, 511, 512, 0><<<dim3(12, 4, B), 512, 0, stream>>>(
        P2H, P2L, WHp, WLp, bn_gamma + 2 * C, bn_beta + 2 * C, bn_mean + 2 * C, bn_var + 2 * C,
        P1H, P1L, nullptr);
    // conv4: x3(P1) -> x4(P2)
    prep_w<<<dim3((3 * 768 * 768 + 255) / 256), 256, 0, stream>>>(w4, WHp, WLp, 768, 3, 768);
    conv_mfma<3, 1, 1, 768, 511, 512, 511, 512, 0><<<dim3(12, 4, B), 512, 0, stream>>>(
        P1H, P1L, WHp, WLp, bn_gamma + 3 * C, bn_beta + 3 * C, bn_mean + 3 * C, bn_var + 3 * C,
        P2H, P2L, nullptr);
    // conv5: x4(P2) -> bufA fp32 [768][511] (EPI=1)
    prep_w<<<dim3((3 * 768 * 768 + 255) / 256), 256, 0, stream>>>(w5, WHp, WLp, 768, 3, 768);
    conv_mfma<3, 1, 1, 768, 511, 512, 511, 511, 1><<<dim3(12, 4, B), 512, 0, stream>>>(
        P2H, P2L, WHp, WLp, bn_gamma + 4 * C, bn_beta + 4 * C, bn_mean + 4 * C, bn_var + 4 * C,
        nullptr, nullptr, bufA);

    conv1x1_bias_T<<<dim3(1, 8, B), 256, 0, stream>>>(bufA, w6, b6, z, C, T2);

    const int Npts = B * T2;
    const int Ntot = Npts * D;
    vq_argmin<<<dim3((Npts + 63) / 64), 256, 0, stream>>>(z, emb, e2p, idx, counts, Npts);
    vq_quant_loss<<<dim3(Ntot / 256), 256, 0, stream>>>(z, emb, idx, (float*)d_out, lossp, Ntot);
    vq_finalize<<<dim3(1), 512, 0, stream>>>(counts, lossp, (float*)d_out, Ntot, Npts);
}

// Round 11
// 2718.090 us; speedup vs baseline: 1.4285x; 1.4285x over previous
//
#include <hip/hip_runtime.h>
#include <cstddef>
#include <cstdint>

#define BN_EPS 1e-5f

typedef _Float16 half8 __attribute__((ext_vector_type(8)));
typedef float f32x4v __attribute__((ext_vector_type(4)));

// pack fp32 (pre-scaled) into fp16 high/low split: v = h + l/2048
__device__ __forceinline__ unsigned split_pack(float v) {
    _Float16 h = (_Float16)v;
    float r = (v - (float)h) * 2048.0f;
    _Float16 l = (_Float16)r;
    unsigned short hu = __builtin_bit_cast(unsigned short, h);
    unsigned short lu = __builtin_bit_cast(unsigned short, l);
    return (unsigned)hu | ((unsigned)lu << 16);
}

// 8 packed (h|l) u32 -> uint4 of 8 h-halfs + uint4 of 8 l-halfs
__device__ __forceinline__ void splitHL(uint4 a, uint4 b2, uint4& h, uint4& l) {
    h.x = (a.x & 0xffffu) | (a.y << 16);
    h.y = (a.z & 0xffffu) | (a.w << 16);
    h.z = (b2.x & 0xffffu) | (b2.y << 16);
    h.w = (b2.z & 0xffffu) | (b2.w << 16);
    l.x = (a.x >> 16) | (a.y & 0xffff0000u);
    l.y = (a.z >> 16) | (a.w & 0xffff0000u);
    l.z = (b2.x >> 16) | (b2.y & 0xffff0000u);
    l.w = (b2.z >> 16) | (b2.w & 0xffff0000u);
}

// ===== prep: w[co][ci][kw] fp32 -> WH/WL [kw][co][CIPAD] u16 planes, x256
__global__ __launch_bounds__(256)
void prep_w(const float* __restrict__ w, unsigned short* __restrict__ wh,
            unsigned short* __restrict__ wl, int Cin, int KW, int CIPAD)
{
    int id = blockIdx.x * 256 + threadIdx.x;
    int total = KW * 768 * CIPAD;
    if (id >= total) return;
    int cip = id % CIPAD;
    int co  = (id / CIPAD) % 768;
    int kw  = id / (CIPAD * 768);
    float v = 0.0f;
    if (cip < Cin) v = w[((size_t)co * Cin + cip) * KW + kw];
    unsigned pk = split_pack(v * 256.0f);
    wh[id] = (unsigned short)pk;
    wl[id] = (unsigned short)(pk >> 16);
}

// ===== prep: mels[b][80][1024] fp32 -> MH/ML [b][1032][96] u16 planes, x16
__global__ __launch_bounds__(256)
void prep_mels(const float* __restrict__ mels, unsigned short* __restrict__ mh,
               unsigned short* __restrict__ ml)
{
    int id = blockIdx.x * 256 + threadIdx.x;
    if (id >= 32 * 1032 * 96) return;
    int c = id % 96;
    int t = (id / 96) % 1032;
    int b = id / (96 * 1032);
    float v = 0.0f;
    if (c < 80 && t < 1024) v = mels[((size_t)b * 80 + c) * 1024 + t];
    unsigned pk = split_pack(v * 16.0f);
    mh[id] = (unsigned short)pk;
    ml[id] = (unsigned short)(pk >> 16);
}

// ===== fp16x3-split MFMA conv + BN + ReLU — 128co x 128t (R9, conv1/2) ======
// R7: 512 thr, wave tile 64x32, one-operand staging, (512,4) -> 64 VGPR,
// 41% occ. R8: pre-split H/L planes, zero staging VALU. R9: lgkm-only
// barrier (neutral). 381 us conv2 = 916 TF (2-barrier structure ceiling).
// R10 LESSON: __launch_bounds__(512,6) caused scratch spills (WRITE 17x,
// MfmaUtil 11%) — never tighten the reg cap below what the K-loop needs.
template<int KW, int S, int P, int CIPAD, int TIN, int TSIN, int TOUT, int TSOUT, int EPI>
__global__ __launch_bounds__(512, 4)
void conv_mfma(const unsigned short* __restrict__ XH, const unsigned short* __restrict__ XL,
               const unsigned short* __restrict__ WH, const unsigned short* __restrict__ WL,
               const float* __restrict__ gamma, const float* __restrict__ beta,
               const float* __restrict__ mean, const float* __restrict__ var,
               unsigned short* __restrict__ OutH, unsigned short* __restrict__ OutL,
               float* __restrict__ Fout)
{
    constexpr int NCI = CIPAD / 32;
    constexpr int NC  = KW * NCI;
    __shared__ unsigned smem[16896];       // 67584 B: planes 2x32KB; bounce [128][132]
    _Float16* sm = (_Float16*)smem;

    const int gx = gridDim.x, gy = gridDim.y;
    const int nwg  = gx * gy * (int)gridDim.z;
    const int flat = blockIdx.x + gx * (blockIdx.y + gy * blockIdx.z);
    const int swz  = (flat & 7) * (nwg >> 3) + (flat >> 3);
    const int cox  = swz % gx;
    const int rem  = swz / gx;
    const int ty   = rem % gy;
    const int b    = rem / gy;

    const int co0 = cox * 128;
    const int t0  = ty * 128;
    const int tid = threadIdx.x;
    const int lane = tid & 63, wv = tid >> 6;
    const int quad = lane >> 4, l16 = lane & 15;
    const int wm = (wv & 1) * 64;
    const int wn = (wv >> 1) * 32;

    f32x4v accH[4][2] = {};
    f32x4v accX[4][2] = {};

    const int ab   = tid >> 8;
    const int r2   = tid & 255;
    const int srow = r2 >> 1;
    const int sh   = r2 & 1;
    const unsigned short* __restrict__ xhb = XH + (size_t)b * TSIN * CIPAD;
    const unsigned short* __restrict__ xlb = XL + (size_t)b * TSIN * CIPAD;

    uint4 rH[2], rL[2];

    auto loadT = [&](int c) {
        const int kw  = c / NCI;
        const int ci0 = (c % NCI) * 32;
        if (ab == 0) {
            const size_t o = (size_t)(kw * 768 + co0 + srow) * CIPAD + ci0;
            rH[0] = *(const uint4*)(WH + o + sh * 8);
            rH[1] = *(const uint4*)(WH + o + (sh + 2) * 8);
            rL[0] = *(const uint4*)(WL + o + sh * 8);
            rL[1] = *(const uint4*)(WL + o + (sh + 2) * 8);
        } else {
            const int tp = (t0 + srow) * S + kw - P;
            rH[0] = rH[1] = rL[0] = rL[1] = make_uint4(0, 0, 0, 0);
            if ((unsigned)tp < (unsigned)TIN) {
                const size_t o = (size_t)tp * CIPAD + ci0;
                rH[0] = *(const uint4*)(xhb + o + sh * 8);
                rH[1] = *(const uint4*)(xhb + o + (sh + 2) * 8);
                rL[0] = *(const uint4*)(xlb + o + sh * 8);
                rL[1] = *(const uint4*)(xlb + o + (sh + 2) * 8);
            }
        }
    };

    auto storeT = [&](int pbuf) {
        const int b0 = pbuf * 16384 + ab * 8192;
        const int u1 = (((srow >> 4) * 4 + sh) * 16 + (srow & 15)) * 8;
        const int u2 = u1 + 256;
        *(uint4*)(sm + b0 + 0    + u1) = rH[0];
        *(uint4*)(sm + b0 + 4096 + u1) = rL[0];
        *(uint4*)(sm + b0 + 0    + u2) = rH[1];
        *(uint4*)(sm + b0 + 4096 + u2) = rL[1];
    };

    auto ldsBarrier = [] {
        asm volatile("s_waitcnt lgkmcnt(0)" ::: "memory");
        __builtin_amdgcn_s_barrier();
        asm volatile("" ::: "memory");
    };

    loadT(0);
    storeT(0);
    if (NC > 1) loadT(1);
    ldsBarrier();

    int p = 0;
    for (int c = 0; c < NC; ++c) {
        const int base = p * 16384;
        if (c + 1 < NC) storeT(p ^ 1);
        if (c + 2 < NC) loadT(c + 2);

        half8 bh[2], bl[2];
#pragma unroll
        for (int nt = 0; nt < 2; ++nt) {
            int gn = (wv >> 1) * 2 + nt;
            int u = ((gn * 4 + quad) * 16 + l16) * 8;
            bh[nt] = *(const half8*)(sm + base + 8192  + u);
            bl[nt] = *(const half8*)(sm + base + 12288 + u);
        }
#pragma unroll
        for (int mt = 0; mt < 4; ++mt) {
            int gm = (wv & 1) * 4 + mt;
            int u = ((gm * 4 + quad) * 16 + l16) * 8;
            half8 ah = *(const half8*)(sm + base + 0    + u);
            half8 al = *(const half8*)(sm + base + 4096 + u);
#pragma unroll
            for (int nt = 0; nt < 2; ++nt) {
                accH[mt][nt] = __builtin_amdgcn_mfma_f32_16x16x32_f16(ah, bh[nt], accH[mt][nt], 0, 0, 0);
                accX[mt][nt] = __builtin_amdgcn_mfma_f32_16x16x32_f16(ah, bl[nt], accX[mt][nt], 0, 0, 0);
                accX[mt][nt] = __builtin_amdgcn_mfma_f32_16x16x32_f16(al, bh[nt], accX[mt][nt], 0, 0, 0);
            }
        }
        ldsBarrier();
        p ^= 1;
    }

    if constexpr (EPI == 0) {
        unsigned* bb = smem;                       // bounce: [t][co], stride 132
#pragma unroll
        for (int mt = 0; mt < 4; ++mt) {
#pragma unroll
            for (int r = 0; r < 4; ++r) {
                int mloc = wm + mt * 16 + quad * 4 + r;
                int co = co0 + mloc;
                float iv = gamma[co] / sqrtf(var[co] + BN_EPS);
                float sh2 = beta[co] - mean[co] * iv;
#pragma unroll
                for (int nt = 0; nt < 2; ++nt) {
                    float vf = (accH[mt][nt][r] + accX[mt][nt][r] * (1.0f / 2048.0f)) * (1.0f / 4096.0f);
                    float y = fmaf(vf, iv, sh2);
                    y = y > 0.0f ? y : 0.0f;
                    bb[(wn + nt * 16 + l16) * 132 + mloc] = split_pack(y * 16.0f);
                }
            }
        }
        __syncthreads();
        int tl = tid >> 2, seg = tid & 3;
        int t = t0 + tl;
        if (t < TOUT) {
            const uint4* src = (const uint4*)(bb + tl * 132 + seg * 32);
            size_t base2 = ((size_t)b * TSOUT + t) * 768 + co0 + seg * 32;
#pragma unroll
            for (int i = 0; i < 4; ++i) {
                uint4 h, l;
                splitHL(src[2 * i], src[2 * i + 1], h, l);
                *(uint4*)(OutH + base2 + i * 8) = h;
                *(uint4*)(OutL + base2 + i * 8) = l;
            }
        }
    } else {
#pragma unroll
        for (int mt = 0; mt < 4; ++mt) {
#pragma unroll
            for (int r = 0; r < 4; ++r) {
                int co = co0 + wm + mt * 16 + quad * 4 + r;
                float iv = gamma[co] / sqrtf(var[co] + BN_EPS);
                float sh2 = beta[co] - mean[co] * iv;
                float* op = Fout + ((size_t)b * 768 + co) * TOUT;
#pragma unroll
                for (int nt = 0; nt < 2; ++nt) {
                    int t = t0 + wn + nt * 16 + l16;
                    if (t < TOUT) {
                        float vf = (accH[mt][nt][r] + accX[mt][nt][r] * (1.0f / 2048.0f)) * (1.0f / 4096.0f);
                        float y = fmaf(vf, iv, sh2);
                        op[t] = y > 0.0f ? y : 0.0f;
                    }
                }
            }
        }
    }
}

// ===== 64co x 128t variant (conv3/4/5): tail-quantization fix ===============
// R9 grid for these convs was 768 blocks / 512 slots = 1.5 rounds -> 2nd
// round at half machine. This variant: grid (12,4,B)=1536 -> EXACT rounds
// at 2/CU (3) or 3/CU (2; LDS 48KB fits 3 if VGPR<=85 — (512,4) cap,
// R10's (512,6) spill avoided). Wave tile 32x32 (acc 2x2). Staging: waves
// 0-3 A (arow=tid>>2, aoct=tid&3), waves 4-7 B (R7 map). Planes per buffer
// (halfs): AH 0, AL 2048, BH 4096, BL 8192; stride 12288. Same formulas,
// numerics bit-identical.
template<int KW, int S, int P, int CIPAD, int TIN, int TSIN, int TOUT, int TSOUT, int EPI>
__global__ __launch_bounds__(512, 4)
void conv_mfma64(const unsigned short* __restrict__ XH, const unsigned short* __restrict__ XL,
                 const unsigned short* __restrict__ WH, const unsigned short* __restrict__ WL,
                 const float* __restrict__ gamma, const float* __restrict__ beta,
                 const float* __restrict__ mean, const float* __restrict__ var,
                 unsigned short* __restrict__ OutH, unsigned short* __restrict__ OutL,
                 float* __restrict__ Fout)
{
    constexpr int NCI = CIPAD / 32;
    constexpr int NC  = KW * NCI;
    __shared__ unsigned smem[12288];       // 49152 B: 2 x 24KB; bounce [128][68]
    _Float16* sm = (_Float16*)smem;

    const int gx = gridDim.x, gy = gridDim.y;
    const int nwg  = gx * gy * (int)gridDim.z;
    const int flat = blockIdx.x + gx * (blockIdx.y + gy * blockIdx.z);
    const int swz  = (flat & 7) * (nwg >> 3) + (flat >> 3);
    const int cox  = swz % gx;
    const int rem  = swz / gx;
    const int ty   = rem % gy;
    const int b    = rem / gy;

    const int co0 = cox * 64;
    const int t0  = ty * 128;
    const int tid = threadIdx.x;
    const int lane = tid & 63, wv = tid >> 6;
    const int quad = lane >> 4, l16 = lane & 15;
    const int wm = (wv & 1) * 32;
    const int wn = (wv >> 1) * 32;

    f32x4v accH[2][2] = {};
    f32x4v accX[2][2] = {};

    const bool isA = tid < 256;
    const int arow = tid >> 2, aoct = tid & 3;       // A: 64 rows x 4 octets
    const int r2   = tid & 255;
    const int srow = r2 >> 1, sh = r2 & 1;           // B: 128 rows, octet pairs
    const unsigned short* __restrict__ xhb = XH + (size_t)b * TSIN * CIPAD;
    const unsigned short* __restrict__ xlb = XL + (size_t)b * TSIN * CIPAD;

    uint4 rH[2], rL[2];

    auto loadT = [&](int c) {
        const int kw  = c / NCI;
        const int ci0 = (c % NCI) * 32;
        if (isA) {
            const size_t o = (size_t)(kw * 768 + co0 + arow) * CIPAD + ci0 + aoct * 8;
            rH[0] = *(const uint4*)(WH + o);
            rL[0] = *(const uint4*)(WL + o);
        } else {
            const int tp = (t0 + srow) * S + kw - P;
            rH[0] = rH[1] = rL[0] = rL[1] = make_uint4(0, 0, 0, 0);
            if ((unsigned)tp < (unsigned)TIN) {
                const size_t o = (size_t)tp * CIPAD + ci0;
                rH[0] = *(const uint4*)(xhb + o + sh * 8);
                rH[1] = *(const uint4*)(xhb + o + (sh + 2) * 8);
                rL[0] = *(const uint4*)(xlb + o + sh * 8);
                rL[1] = *(const uint4*)(xlb + o + (sh + 2) * 8);
            }
        }
    };

    auto storeT = [&](int pbuf) {
        const int b0 = pbuf * 12288;
        if (isA) {
            const int u = ((arow >> 4) * 4 + aoct) * 128 + (arow & 15) * 8;
            *(uint4*)(sm + b0 + 0    + u) = rH[0];
            *(uint4*)(sm + b0 + 2048 + u) = rL[0];
        } else {
            const int u1 = ((srow >> 4) * 4 + sh) * 128 + (srow & 15) * 8;
            const int u2 = u1 + 256;
            *(uint4*)(sm + b0 + 4096 + u1) = rH[0];
            *(uint4*)(sm + b0 + 8192 + u1) = rL[0];
            *(uint4*)(sm + b0 + 4096 + u2) = rH[1];
            *(uint4*)(sm + b0 + 8192 + u2) = rL[1];
        }
    };

    auto ldsBarrier = [] {
        asm volatile("s_waitcnt lgkmcnt(0)" ::: "memory");
        __builtin_amdgcn_s_barrier();
        asm volatile("" ::: "memory");
    };

    loadT(0);
    storeT(0);
    if (NC > 1) loadT(1);
    ldsBarrier();

    int p = 0;
    for (int c = 0; c < NC; ++c) {
        const int base = p * 12288;
        if (c + 1 < NC) storeT(p ^ 1);
        if (c + 2 < NC) loadT(c + 2);

        half8 bh[2], bl[2];
#pragma unroll
        for (int nt = 0; nt < 2; ++nt) {
            int gn = (wv >> 1) * 2 + nt;
            int u = (gn * 4 + quad) * 128 + l16 * 8;
            bh[nt] = *(const half8*)(sm + base + 4096 + u);
            bl[nt] = *(const half8*)(sm + base + 8192 + u);
        }
#pragma unroll
        for (int mt = 0; mt < 2; ++mt) {
            int gm = (wv & 1) * 2 + mt;
            int u = (gm * 4 + quad) * 128 + l16 * 8;
            half8 ah = *(const half8*)(sm + base + 0    + u);
            half8 al = *(const half8*)(sm + base + 2048 + u);
#pragma unroll
            for (int nt = 0; nt < 2; ++nt) {
                accH[mt][nt] = __builtin_amdgcn_mfma_f32_16x16x32_f16(ah, bh[nt], accH[mt][nt], 0, 0, 0);
                accX[mt][nt] = __builtin_amdgcn_mfma_f32_16x16x32_f16(ah, bl[nt], accX[mt][nt], 0, 0, 0);
                accX[mt][nt] = __builtin_amdgcn_mfma_f32_16x16x32_f16(al, bh[nt], accX[mt][nt], 0, 0, 0);
            }
        }
        ldsBarrier();
        p ^= 1;
    }

    if constexpr (EPI == 0) {
        unsigned* bb = smem;                       // bounce: [t 128][co 64 +4 pad]
#pragma unroll
        for (int mt = 0; mt < 2; ++mt) {
#pragma unroll
            for (int r = 0; r < 4; ++r) {
                int mloc = wm + mt * 16 + quad * 4 + r;
                int co = co0 + mloc;
                float iv = gamma[co] / sqrtf(var[co] + BN_EPS);
                float sh2 = beta[co] - mean[co] * iv;
#pragma unroll
                for (int nt = 0; nt < 2; ++nt) {
                    float vf = (accH[mt][nt][r] + accX[mt][nt][r] * (1.0f / 2048.0f)) * (1.0f / 4096.0f);
                    float y = fmaf(vf, iv, sh2);
                    y = y > 0.0f ? y : 0.0f;
                    bb[(wn + nt * 16 + l16) * 68 + mloc] = split_pack(y * 16.0f);
                }
            }
        }
        __syncthreads();
        int tl = tid >> 2, seg = tid & 3;          // 128 rows x 4 segs of 16 co
        int t = t0 + tl;
        if (t < TOUT) {
            const uint4* src = (const uint4*)(bb + tl * 68 + seg * 16);
            size_t base2 = ((size_t)b * TSOUT + t) * 768 + co0 + seg * 16;
#pragma unroll
            for (int i = 0; i < 2; ++i) {
                uint4 h, l;
                splitHL(src[2 * i], src[2 * i + 1], h, l);
                *(uint4*)(OutH + base2 + i * 8) = h;
                *(uint4*)(OutL + base2 + i * 8) = l;
            }
        }
    } else {
#pragma unroll
        for (int mt = 0; mt < 2; ++mt) {
#pragma unroll
            for (int r = 0; r < 4; ++r) {
                int co = co0 + wm + mt * 16 + quad * 4 + r;
                float iv = gamma[co] / sqrtf(var[co] + BN_EPS);
                float sh2 = beta[co] - mean[co] * iv;
                float* op = Fout + ((size_t)b * 768 + co) * TOUT;
#pragma unroll
                for (int nt = 0; nt < 2; ++nt) {
                    int t = t0 + wn + nt * 16 + l16;
                    if (t < TOUT) {
                        float vf = (accH[mt][nt][r] + accX[mt][nt][r] * (1.0f / 2048.0f)) * (1.0f / 4096.0f);
                        float y = fmaf(vf, iv, sh2);
                        op[t] = y > 0.0f ? y : 0.0f;
                    }
                }
            }
        }
    }
}

// ================= 1x1 conv (C=768 -> D=64) + bias, output z[b][t][d] =======
constexpr int TM = 64, TN = 64, TK = 16;

__global__ __launch_bounds__(256)
void conv1x1_bias_T(const float* __restrict__ in, const float* __restrict__ w,
                    const float* __restrict__ bias, float* __restrict__ z,
                    int Cin, int T)
{
    const int b   = blockIdx.z;
    const int t0  = blockIdx.y * TN;
    const int tid = threadIdx.x;

    __shared__ float As[TK][TM + 4];
    __shared__ float Bs[TK][TN + 4];

    float acc[4][4] = {};

    const int m0 = (tid & 15) * 4;
    const int n0 = (tid >> 4) * 4;

    const float* __restrict__ inb = in + (size_t)b * Cin * T;

    const int a_m = tid >> 4;
    const int a_k = tid & 15;
    const int b_k = tid >> 6;
    const int b_n = tid & 63;

    for (int kc = 0; kc < Cin; kc += TK) {
        __syncthreads();
#pragma unroll
        for (int i = 0; i < 4; ++i) {
            int m = a_m + 16 * i;
            As[a_k][m] = w[(size_t)m * Cin + kc + a_k];
        }
#pragma unroll
        for (int i = 0; i < 4; ++i) {
            int kk = b_k + 4 * i;
            int ci = kc + kk;
            int t  = t0 + b_n;
            Bs[kk][b_n] = (t < T) ? inb[(size_t)ci * T + t] : 0.0f;
        }
        __syncthreads();
#pragma unroll
        for (int kk = 0; kk < TK; ++kk) {
            float4 av = *reinterpret_cast<const float4*>(&As[kk][m0]);
            float4 bv = *reinterpret_cast<const float4*>(&Bs[kk][n0]);
            float am[4] = {av.x, av.y, av.z, av.w};
            float bn[4] = {bv.x, bv.y, bv.z, bv.w};
#pragma unroll
            for (int mi = 0; mi < 4; ++mi)
#pragma unroll
                for (int nj = 0; nj < 4; ++nj)
                    acc[mi][nj] = fmaf(am[mi], bn[nj], acc[mi][nj]);
        }
    }

    float4 bb = *reinterpret_cast<const float4*>(&bias[m0]);
    float bs[4] = {bb.x, bb.y, bb.z, bb.w};
#pragma unroll
    for (int nj = 0; nj < 4; ++nj) {
        int t = t0 + n0 + nj;
        if (t < T) {
            float4 v;
            v.x = acc[0][nj] + bs[0];
            v.y = acc[1][nj] + bs[1];
            v.z = acc[2][nj] + bs[2];
            v.w = acc[3][nj] + bs[3];
            *reinterpret_cast<float4*>(&z[((size_t)b * T + t) * 64 + m0]) = v;
        }
    }
}

// ============================== VQ kernels ==================================
__global__ __launch_bounds__(256)
void vq_e2(const float* __restrict__ emb, float* __restrict__ e2)
{
    int m = blockIdx.x * 256 + threadIdx.x;
    if (m < 512) {
        float s = 0.0f;
#pragma unroll
        for (int d = 0; d < 64; ++d) {
            float v = emb[(size_t)m * 64 + d];
            s = fmaf(v, v, s);
        }
        e2[m] = s;
    }
}

// R9 (kept): 256 thr (4 waves) per 64 points; codebook split across waves,
// lexicographic (dist, idx) merge == argmin-first semantics.
__global__ __launch_bounds__(256)
void vq_argmin(const float* __restrict__ z, const float* __restrict__ emb,
               const float* __restrict__ e2, int* __restrict__ idx,
               float* __restrict__ counts, int N)
{
    __shared__ float Es[256 * 64];        // 64KB
    __shared__ float bestS[4][64];
    __shared__ int   biS[4][64];
    const int tid = threadIdx.x;
    const int pt  = tid & 63;
    const int wvq = tid >> 6;
    const int n   = blockIdx.x * 64 + pt;
    const bool act = n < N;

    float x[64];
    float x2 = 0.0f;
    if (act) {
        const float4* zp = reinterpret_cast<const float4*>(z + (size_t)n * 64);
#pragma unroll
        for (int i = 0; i < 16; ++i) {
            float4 v = zp[i];
            x[4 * i + 0] = v.x; x[4 * i + 1] = v.y;
            x[4 * i + 2] = v.z; x[4 * i + 3] = v.w;
        }
#pragma unroll
        for (int d = 0; d < 64; ++d) x2 = fmaf(x[d], x[d], x2);
    }

    float best = 3.4e38f;
    int   bi   = 0;
    for (int pass = 0; pass < 2; ++pass) {
        __syncthreads();
        const float4* ep  = reinterpret_cast<const float4*>(emb + (size_t)pass * 16384);
        float4*       esp = reinterpret_cast<float4*>(Es);
#pragma unroll
        for (int i = 0; i < 16; ++i) esp[tid + 256 * i] = ep[tid + 256 * i];
        __syncthreads();
        const int c = pass * 4 + wvq;
        for (int r = 0; r < 64; ++r) {
            const float4* er = reinterpret_cast<const float4*>(&Es[((size_t)wvq * 64 + r) * 64]);
            float dot = 0.0f;
#pragma unroll
            for (int i = 0; i < 16; ++i) {
                float4 e4 = er[i];
                dot = fmaf(x[4 * i + 0], e4.x, dot);
                dot = fmaf(x[4 * i + 1], e4.y, dot);
                dot = fmaf(x[4 * i + 2], e4.z, dot);
                dot = fmaf(x[4 * i + 3], e4.w, dot);
            }
            float dist = (e2[c * 64 + r] + x2) - 2.0f * dot;  // reference op order
            if (dist < best) { best = dist; bi = c * 64 + r; }
        }
    }
    bestS[wvq][pt] = best;
    biS[wvq][pt]   = bi;
    __syncthreads();
    if (wvq == 0 && act) {
        float bd = bestS[0][pt];
        int   bx = biS[0][pt];
#pragma unroll
        for (int g = 1; g < 4; ++g) {
            float d = bestS[g][pt];
            int   i2 = biS[g][pt];
            if (d < bd || (d == bd && i2 < bx)) { bd = d; bx = i2; }
        }
        idx[n] = bx;
        atomicAdd(&counts[bx], 1.0f);
    }
}

__global__ __launch_bounds__(256)
void vq_quant_loss(const float* __restrict__ z, const float* __restrict__ emb,
                   const int* __restrict__ idx, float* __restrict__ qout,
                   double* __restrict__ loss_sum, int Ntot)
{
    int g = blockIdx.x * 256 + threadIdx.x;
    float d2 = 0.0f;
    if (g < Ntot) {
        int n = g >> 6;
        int d = g & 63;
        float q  = emb[(size_t)idx[n] * 64 + d];
        float zv = z[g];
        qout[g] = zv + (q - zv);
        float diff = zv - q;
        d2 = diff * diff;
    }
#pragma unroll
    for (int o = 32; o > 0; o >>= 1) d2 += __shfl_down(d2, o);
    __shared__ float wsum[4];
    if ((threadIdx.x & 63) == 0) wsum[threadIdx.x >> 6] = d2;
    __syncthreads();
    if (threadIdx.x == 0)
        atomicAdd(loss_sum, (double)(wsum[0] + wsum[1] + wsum[2] + wsum[3]));
}

__global__ __launch_bounds__(512)
void vq_finalize(const float* __restrict__ counts, const double* __restrict__ loss_sum,
                 float* __restrict__ out, int Ntot, int Npts)
{
    int t = threadIdx.x;
    float c   = counts[t];
    float avg = c / (float)Npts;
    float term = avg * logf(avg + 1e-10f);
#pragma unroll
    for (int o = 32; o > 0; o >>= 1) term += __shfl_down(term, o);
    __shared__ float wsum[8];
    if ((t & 63) == 0) wsum[t >> 6] = term;
    __syncthreads();
    if (t == 0) {
        float s = 0.0f;
        for (int i = 0; i < 8; ++i) s += wsum[i];
        out[Ntot]     = 0.25f * (float)(loss_sum[0] / (double)Ntot);
        out[Ntot + 1] = expf(-s);
    }
}

// ================================ launcher ==================================
extern "C" void kernel_launch(void* const* d_in, const int* in_sizes, int n_in,
                              void* d_out, int out_size, void* d_ws, size_t ws_size,
                              hipStream_t stream)
{
    const float* mels     = (const float*)d_in[0];
    const float* w1       = (const float*)d_in[1];
    const float* w2       = (const float*)d_in[2];
    const float* w3       = (const float*)d_in[3];
    const float* w4       = (const float*)d_in[4];
    const float* w5       = (const float*)d_in[5];
    const float* w6       = (const float*)d_in[6];
    const float* b6       = (const float*)d_in[7];
    const float* bn_gamma = (const float*)d_in[8];
    const float* bn_beta  = (const float*)d_in[9];
    const float* bn_mean  = (const float*)d_in[10];
    const float* bn_var   = (const float*)d_in[11];
    const float* emb      = (const float*)d_in[12];

    constexpr int B = 32, C = 768, D = 64, T2 = 511;

    // Activations as H/L u16 planes [b][1024][768] (50,331,648 B each).
    char* ws = (char*)d_ws;
    constexpr size_t ACT = (size_t)32 * 1024 * 768;            // halfs per plane
    unsigned short* P1H = (unsigned short*)ws;
    unsigned short* P1L = P1H + ACT;
    unsigned short* P2H = (unsigned short*)(ws + 100663296);
    unsigned short* P2L = P2H + ACT;
    unsigned short* WHp = (unsigned short*)(ws + 201326592);   // 4,718,592 B (max KW=4)
    unsigned short* WLp = WHp + (size_t)4 * 768 * 768;         // 4,718,592 B
    size_t misc  = 201326592 + 9437184;
    float*  counts = (float*)(ws + misc);              // 2048 B
    double* lossp  = (double*)(ws + misc + 2048);      // 8 B (+pad)
    float*  e2p    = (float*)(ws + misc + 2048 + 64);  // 2048 B
    int*    idx    = (int*)(ws + misc + 2048 + 64 + 2048);  // 65,408 B

    unsigned short* MH = P2H;                          // mels planes (dead before conv2 out)
    unsigned short* ML = P2L;
    float* bufA = (float*)ws;                          // conv5 fp32 out (P1 dead)
    float* z    = (float*)(ws + 100663296);            // conv6 out (P2 dead)

    hipMemsetAsync(ws + misc, 0, 2048 + 64, stream);   // counts + loss

    vq_e2<<<dim3(2), 256, 0, stream>>>(emb, e2p);
    prep_mels<<<dim3((32 * 1032 * 96 + 255) / 256), 256, 0, stream>>>(mels, MH, ML);

    // conv1: Cin 80 (pad 96), KW 3, S1 P0, in MH/ML[1032][96] -> x1 = P1 [1024][768]
    prep_w<<<dim3((3 * 768 * 96 + 255) / 256), 256, 0, stream>>>(w1, WHp, WLp, 80, 3, 96);
    conv_mfma<3, 1, 0, 96, 1032, 1032, 1022, 1024, 0><<<dim3(6, 8, B), 512, 0, stream>>>(
        MH, ML, WHp, WLp, bn_gamma + 0 * C, bn_beta + 0 * C, bn_mean + 0 * C, bn_var + 0 * C,
        P1H, P1L, nullptr);
    // conv2: x1(P1) -> x2(P2)  [1536 blocks = 3 exact rounds @2/CU]
    prep_w<<<dim3((3 * 768 * 768 + 255) / 256), 256, 0, stream>>>(w2, WHp, WLp, 768, 3, 768);
    conv_mfma<3, 1, 1, 768, 1022, 1024, 1022, 1024, 0><<<dim3(6, 8, B), 512, 0, stream>>>(
        P1H, P1L, WHp, WLp, bn_gamma + 1 * C, bn_beta + 1 * C, bn_mean + 1 * C, bn_var + 1 * C,
        P2H, P2L, nullptr);
    // conv3/4/5: 64co tile, grid (12,4,B)=1536 -> exact rounds (tail fix)
    prep_w<<<dim3((4 * 768 * 768 + 255) / 256), 256, 0, stream>>>(w3, WHp, WLp, 768, 4, 768);
    conv_mfma64<4, 2, 1, 768, 1022, 1024, 511, 512, 0><<<dim3(12, 4, B), 512, 0, stream>>>(
        P2H, P2L, WHp, WLp, bn_gamma + 2 * C, bn_beta + 2 * C, bn_mean + 2 * C, bn_var + 2 * C,
        P1H, P1L, nullptr);
    prep_w<<<dim3((3 * 768 * 768 + 255) / 256), 256, 0, stream>>>(w4, WHp, WLp, 768, 3, 768);
    conv_mfma64<3, 1, 1, 768, 511, 512, 511, 512, 0><<<dim3(12, 4, B), 512, 0, stream>>>(
        P1H, P1L, WHp, WLp, bn_gamma + 3 * C, bn_beta + 3 * C, bn_mean + 3 * C, bn_var + 3 * C,
        P2H, P2L, nullptr);
    prep_w<<<dim3((3 * 768 * 768 + 255) / 256), 256, 0, stream>>>(w5, WHp, WLp, 768, 3, 768);
    conv_mfma64<3, 1, 1, 768, 511, 512, 511, 511, 1><<<dim3(12, 4, B), 512, 0, stream>>>(
        P2H, P2L, WHp, WLp, bn_gamma + 4 * C, bn_beta + 4 * C, bn_mean + 4 * C, bn_var + 4 * C,
        nullptr, nullptr, bufA);

    conv1x1_bias_T<<<dim3(1, 8, B), 256, 0, stream>>>(bufA, w6, b6, z, C, T2);

    const int Npts = B * T2;
    const int Ntot = Npts * D;
    vq_argmin<<<dim3((Npts + 63) / 64), 256, 0, stream>>>(z, emb, e2p, idx, counts, Npts);
    vq_quant_loss<<<dim3(Ntot / 256), 256, 0, stream>>>(z, emb, idx, (float*)d_out, lossp, Ntot);
    vq_finalize<<<dim3(1), 512, 0, stream>>>(counts, lossp, (float*)d_out, Ntot, Npts);
}

// Round 12
// 1379.298 us; speedup vs baseline: 2.8151x; 1.9706x over previous
//
#include <hip/hip_runtime.h>
#include <cstddef>
#include <cstdint>

#define BN_EPS 1e-5f

typedef _Float16 half8 __attribute__((ext_vector_type(8)));
typedef float f32x4v __attribute__((ext_vector_type(4)));

// pack fp32 (pre-scaled) into fp16 high/low split: v = h + l/2048
__device__ __forceinline__ unsigned split_pack(float v) {
    _Float16 h = (_Float16)v;
    float r = (v - (float)h) * 2048.0f;
    _Float16 l = (_Float16)r;
    unsigned short hu = __builtin_bit_cast(unsigned short, h);
    unsigned short lu = __builtin_bit_cast(unsigned short, l);
    return (unsigned)hu | ((unsigned)lu << 16);
}

// 8 packed (h|l) u32 -> uint4 of 8 h-halfs + uint4 of 8 l-halfs
__device__ __forceinline__ void splitHL(uint4 a, uint4 b2, uint4& h, uint4& l) {
    h.x = (a.x & 0xffffu) | (a.y << 16);
    h.y = (a.z & 0xffffu) | (a.w << 16);
    h.z = (b2.x & 0xffffu) | (b2.y << 16);
    h.w = (b2.z & 0xffffu) | (b2.w << 16);
    l.x = (a.x >> 16) | (a.y & 0xffff0000u);
    l.y = (a.z >> 16) | (a.w & 0xffff0000u);
    l.z = (b2.x >> 16) | (b2.y & 0xffff0000u);
    l.w = (b2.z >> 16) | (b2.w & 0xffff0000u);
}

// ===== prep: w[co][ci][kw] fp32 -> WH/WL [kw][co][CIPAD] u16 planes, x256
__global__ __launch_bounds__(256)
void prep_w(const float* __restrict__ w, unsigned short* __restrict__ wh,
            unsigned short* __restrict__ wl, int Cin, int KW, int CIPAD)
{
    int id = blockIdx.x * 256 + threadIdx.x;
    int total = KW * 768 * CIPAD;
    if (id >= total) return;
    int cip = id % CIPAD;
    int co  = (id / CIPAD) % 768;
    int kw  = id / (CIPAD * 768);
    float v = 0.0f;
    if (cip < Cin) v = w[((size_t)co * Cin + cip) * KW + kw];
    unsigned pk = split_pack(v * 256.0f);
    wh[id] = (unsigned short)pk;
    wl[id] = (unsigned short)(pk >> 16);
}

// ===== prep: mels[b][80][1024] fp32 -> MH/ML [b][1032][96] u16 planes, x16
__global__ __launch_bounds__(256)
void prep_mels(const float* __restrict__ mels, unsigned short* __restrict__ mh,
               unsigned short* __restrict__ ml)
{
    int id = blockIdx.x * 256 + threadIdx.x;
    if (id >= 32 * 1032 * 96) return;
    int c = id % 96;
    int t = (id / 96) % 1032;
    int b = id / (96 * 1032);
    float v = 0.0f;
    if (c < 80 && t < 1024) v = mels[((size_t)b * 80 + c) * 1024 + t];
    unsigned pk = split_pack(v * 16.0f);
    mh[id] = (unsigned short)pk;
    ml[id] = (unsigned short)(pk >> 16);
}

// ===== fp16x3-split MFMA conv + BN + ReLU — R9 config (session best) =========
// 512 thr (8 waves), tile 128co x 128t, wave tile 64co x 32t (acc 4x2),
// thread stages ONE operand (ab=tid>>8), __launch_bounds__(512,4) -> 64
// VGPR, 41% occupancy. Pre-split global H/L u16 planes: staging is pure
// load->ds_write, zero VALU on the chain. lgkm-only barrier (neutral but
// harmless). conv2 = 379-386 us = 916 TF effective MFMA — the documented
// ~900 TF ceiling of the 2-barrier-per-K-step structure.
// VALIDATED-OPTIMUM NOTE: every alternative tried regressed —
//   R1 global_load_lds staging (-28%), R3 global->reg A (-41%),
//   R4 kw-inner (-7%), R5 phase rotation+setprio (-47%),
//   R6 staging-write remap (-10%, broke load coalescing),
//   R10 64co tile @(512,6) (scratch spill, WRITE 17x),
//   R11 64co tile @(512,4) conv3/4/5 (-2.2x: worse LDS ratio + A-write
//       4-way conflict + never reached 3 blocks/CU).
// Wins kept: R2 XCD swizzle (FETCH -67%), R7 8-wave occupancy (+23%),
// R8 pre-split planes (VALU 42->30), R9 4-wave vq_argmin (-75 us).
// A = weights (x256), B = acts (x16); result=(accHH+accX/2048)/4096.
// C/D layout (m89): col=lane&15, row=quad*4+reg.
// EPI=0: H/L u16 planes [t][768] via packed bounce; EPI=1: fp32 [co][TOUT].
template<int KW, int S, int P, int CIPAD, int TIN, int TSIN, int TOUT, int TSOUT, int EPI>
__global__ __launch_bounds__(512, 4)
void conv_mfma(const unsigned short* __restrict__ XH, const unsigned short* __restrict__ XL,
               const unsigned short* __restrict__ WH, const unsigned short* __restrict__ WL,
               const float* __restrict__ gamma, const float* __restrict__ beta,
               const float* __restrict__ mean, const float* __restrict__ var,
               unsigned short* __restrict__ OutH, unsigned short* __restrict__ OutL,
               float* __restrict__ Fout)
{
    constexpr int NCI = CIPAD / 32;
    constexpr int NC  = KW * NCI;          // >= 9 for all convs
    __shared__ unsigned smem[16896];       // 67584 B: planes 2x32KB; bounce [128][132]
    _Float16* sm = (_Float16*)smem;
    // per-buffer plane offsets (halfs): AH 0, AL 4096, BH 8192, BL 12288; buf stride 16384
    // plane layout: 16B-unit u = (tile16*4 + kquad)*16 + l16  (tile16 = row>>4, l16 = row&15)

    // --- XCD-aware bijective swizzle (cox fastest within an XCD chunk) ---
    const int gx = gridDim.x, gy = gridDim.y;
    const int nwg  = gx * gy * (int)gridDim.z;       // % 8 == 0 for all launches
    const int flat = blockIdx.x + gx * (blockIdx.y + gy * blockIdx.z);
    const int swz  = (flat & 7) * (nwg >> 3) + (flat >> 3);
    const int cox  = swz % gx;
    const int rem  = swz / gx;
    const int ty   = rem % gy;
    const int b    = rem / gy;

    const int co0 = cox * 128;
    const int t0  = ty * 128;
    const int tid = threadIdx.x;
    const int lane = tid & 63, wv = tid >> 6;        // wv 0..7
    const int quad = lane >> 4, l16 = lane & 15;
    const int wm = (wv & 1) * 64;                    // 2 M-groups of 64
    const int wn = (wv >> 1) * 32;                   // 4 N-groups of 32

    f32x4v accH[4][2] = {};
    f32x4v accX[4][2] = {};

    // staging: thread owns ONE operand segment (R2 row/octet map per operand)
    const int ab   = tid >> 8;             // 0 = A (weights), 1 = B (acts)
    const int r2   = tid & 255;
    const int srow = r2 >> 1;              // 0..127
    const int sh   = r2 & 1;               // owns k-quads {sh, sh+2}
    const unsigned short* __restrict__ xhb = XH + (size_t)b * TSIN * CIPAD;
    const unsigned short* __restrict__ xlb = XL + (size_t)b * TSIN * CIPAD;

    uint4 rH[2], rL[2];

    auto loadT = [&](int c) {
        const int kw  = c / NCI;           // kw-major (R2 order)
        const int ci0 = (c % NCI) * 32;
        if (ab == 0) {
            const size_t o = (size_t)(kw * 768 + co0 + srow) * CIPAD + ci0;
            rH[0] = *(const uint4*)(WH + o + sh * 8);        // quad sh (8 halfs)
            rH[1] = *(const uint4*)(WH + o + (sh + 2) * 8);  // quad sh+2
            rL[0] = *(const uint4*)(WL + o + sh * 8);
            rL[1] = *(const uint4*)(WL + o + (sh + 2) * 8);
        } else {
            const int tp = (t0 + srow) * S + kw - P;
            rH[0] = rH[1] = rL[0] = rL[1] = make_uint4(0, 0, 0, 0);
            if ((unsigned)tp < (unsigned)TIN) {
                const size_t o = (size_t)tp * CIPAD + ci0;
                rH[0] = *(const uint4*)(xhb + o + sh * 8);
                rH[1] = *(const uint4*)(xhb + o + (sh + 2) * 8);
                rL[0] = *(const uint4*)(xlb + o + sh * 8);
                rL[1] = *(const uint4*)(xlb + o + (sh + 2) * 8);
            }
        }
    };

    auto storeT = [&](int pbuf) {
        const int b0 = pbuf * 16384 + ab * 8192;   // operand plane pair base
        const int u1 = (((srow >> 4) * 4 + sh) * 16 + (srow & 15)) * 8;  // halfs
        const int u2 = u1 + 256;                                          // q = sh+2
        *(uint4*)(sm + b0 + 0    + u1) = rH[0];
        *(uint4*)(sm + b0 + 4096 + u1) = rL[0];
        *(uint4*)(sm + b0 + 0    + u2) = rH[1];
        *(uint4*)(sm + b0 + 4096 + u2) = rL[1];
    };

    // LDS-only barrier: drains ds ops (lgkmcnt) but NOT in-flight global
    // register loads (vmcnt) — private VGPR dest; consumer is next storeT.
    auto ldsBarrier = [] {
        asm volatile("s_waitcnt lgkmcnt(0)" ::: "memory");
        __builtin_amdgcn_s_barrier();
        asm volatile("" ::: "memory");
    };

    loadT(0);
    storeT(0);
    if (NC > 1) loadT(1);
    ldsBarrier();

    int p = 0;
    for (int c = 0; c < NC; ++c) {
        const int base = p * 16384;
        if (c + 1 < NC) storeT(p ^ 1);     // drains reg set into other buffer
        if (c + 2 < NC) loadT(c + 2);      // refills reg set; in flight across barrier

        half8 bh[2], bl[2];
#pragma unroll
        for (int nt = 0; nt < 2; ++nt) {
            int gn = (wv >> 1) * 2 + nt;   // 0..7
            int u = ((gn * 4 + quad) * 16 + l16) * 8;
            bh[nt] = *(const half8*)(sm + base + 8192  + u);
            bl[nt] = *(const half8*)(sm + base + 12288 + u);
        }
#pragma unroll
        for (int mt = 0; mt < 4; ++mt) {
            int gm = (wv & 1) * 4 + mt;    // 0..7
            int u = ((gm * 4 + quad) * 16 + l16) * 8;
            half8 ah = *(const half8*)(sm + base + 0    + u);
            half8 al = *(const half8*)(sm + base + 4096 + u);
#pragma unroll
            for (int nt = 0; nt < 2; ++nt) {
                accH[mt][nt] = __builtin_amdgcn_mfma_f32_16x16x32_f16(ah, bh[nt], accH[mt][nt], 0, 0, 0);
                accX[mt][nt] = __builtin_amdgcn_mfma_f32_16x16x32_f16(ah, bl[nt], accX[mt][nt], 0, 0, 0);
                accX[mt][nt] = __builtin_amdgcn_mfma_f32_16x16x32_f16(al, bh[nt], accX[mt][nt], 0, 0, 0);
            }
        }
        ldsBarrier();                      // reads of p + ds_writes to p^1 drained
        p ^= 1;
    }

    if constexpr (EPI == 0) {
        unsigned* bb = smem;                       // bounce: [t_local][co_local], stride 132
#pragma unroll
        for (int mt = 0; mt < 4; ++mt) {
#pragma unroll
            for (int r = 0; r < 4; ++r) {
                int mloc = wm + mt * 16 + quad * 4 + r;   // C/D row = co_local
                int co = co0 + mloc;
                float iv = gamma[co] / sqrtf(var[co] + BN_EPS);
                float sh2 = beta[co] - mean[co] * iv;
#pragma unroll
                for (int nt = 0; nt < 2; ++nt) {
                    float vf = (accH[mt][nt][r] + accX[mt][nt][r] * (1.0f / 2048.0f)) * (1.0f / 4096.0f);
                    float y = fmaf(vf, iv, sh2);
                    y = y > 0.0f ? y : 0.0f;
                    bb[(wn + nt * 16 + l16) * 132 + mloc] = split_pack(y * 16.0f);
                }
            }
        }
        __syncthreads();
        int tl = tid >> 2, seg = tid & 3;          // 128 rows x 4 segs of 32 co
        int t = t0 + tl;
        if (t < TOUT) {
            const uint4* src = (const uint4*)(bb + tl * 132 + seg * 32);
            size_t base2 = ((size_t)b * TSOUT + t) * 768 + co0 + seg * 32;   // half idx
#pragma unroll
            for (int i = 0; i < 4; ++i) {
                uint4 h, l;
                splitHL(src[2 * i], src[2 * i + 1], h, l);
                *(uint4*)(OutH + base2 + i * 8) = h;
                *(uint4*)(OutL + base2 + i * 8) = l;
            }
        }
    } else {
#pragma unroll
        for (int mt = 0; mt < 4; ++mt) {
#pragma unroll
            for (int r = 0; r < 4; ++r) {
                int co = co0 + wm + mt * 16 + quad * 4 + r;
                float iv = gamma[co] / sqrtf(var[co] + BN_EPS);
                float sh2 = beta[co] - mean[co] * iv;
                float* op = Fout + ((size_t)b * 768 + co) * TOUT;
#pragma unroll
                for (int nt = 0; nt < 2; ++nt) {
                    int t = t0 + wn + nt * 16 + l16;
                    if (t < TOUT) {
                        float vf = (accH[mt][nt][r] + accX[mt][nt][r] * (1.0f / 2048.0f)) * (1.0f / 4096.0f);
                        float y = fmaf(vf, iv, sh2);
                        op[t] = y > 0.0f ? y : 0.0f;
                    }
                }
            }
        }
    }
}

// ================= 1x1 conv (C=768 -> D=64) + bias, output z[b][t][d] =======
constexpr int TM = 64, TN = 64, TK = 16;

__global__ __launch_bounds__(256)
void conv1x1_bias_T(const float* __restrict__ in, const float* __restrict__ w,
                    const float* __restrict__ bias, float* __restrict__ z,
                    int Cin, int T)
{
    const int b   = blockIdx.z;
    const int t0  = blockIdx.y * TN;
    const int tid = threadIdx.x;

    __shared__ float As[TK][TM + 4];
    __shared__ float Bs[TK][TN + 4];

    float acc[4][4] = {};

    const int m0 = (tid & 15) * 4;
    const int n0 = (tid >> 4) * 4;

    const float* __restrict__ inb = in + (size_t)b * Cin * T;

    const int a_m = tid >> 4;
    const int a_k = tid & 15;
    const int b_k = tid >> 6;
    const int b_n = tid & 63;

    for (int kc = 0; kc < Cin; kc += TK) {
        __syncthreads();
#pragma unroll
        for (int i = 0; i < 4; ++i) {
            int m = a_m + 16 * i;
            As[a_k][m] = w[(size_t)m * Cin + kc + a_k];
        }
#pragma unroll
        for (int i = 0; i < 4; ++i) {
            int kk = b_k + 4 * i;
            int ci = kc + kk;
            int t  = t0 + b_n;
            Bs[kk][b_n] = (t < T) ? inb[(size_t)ci * T + t] : 0.0f;
        }
        __syncthreads();
#pragma unroll
        for (int kk = 0; kk < TK; ++kk) {
            float4 av = *reinterpret_cast<const float4*>(&As[kk][m0]);
            float4 bv = *reinterpret_cast<const float4*>(&Bs[kk][n0]);
            float am[4] = {av.x, av.y, av.z, av.w};
            float bn[4] = {bv.x, bv.y, bv.z, bv.w};
#pragma unroll
            for (int mi = 0; mi < 4; ++mi)
#pragma unroll
                for (int nj = 0; nj < 4; ++nj)
                    acc[mi][nj] = fmaf(am[mi], bn[nj], acc[mi][nj]);
        }
    }

    float4 bb = *reinterpret_cast<const float4*>(&bias[m0]);
    float bs[4] = {bb.x, bb.y, bb.z, bb.w};
#pragma unroll
    for (int nj = 0; nj < 4; ++nj) {
        int t = t0 + n0 + nj;
        if (t < T) {
            float4 v;
            v.x = acc[0][nj] + bs[0];
            v.y = acc[1][nj] + bs[1];
            v.z = acc[2][nj] + bs[2];
            v.w = acc[3][nj] + bs[3];
            *reinterpret_cast<float4*>(&z[((size_t)b * T + t) * 64 + m0]) = v;
        }
    }
}

// ============================== VQ kernels ==================================
__global__ __launch_bounds__(256)
void vq_e2(const float* __restrict__ emb, float* __restrict__ e2)
{
    int m = blockIdx.x * 256 + threadIdx.x;
    if (m < 512) {
        float s = 0.0f;
#pragma unroll
        for (int d = 0; d < 64; ++d) {
            float v = emb[(size_t)m * 64 + d];
            s = fmaf(v, v, s);
        }
        e2[m] = s;
    }
}

// R9: 256 thr (4 waves) per 64 points; codebook split across waves,
// lexicographic (dist, idx) merge == argmin-first semantics.
__global__ __launch_bounds__(256)
void vq_argmin(const float* __restrict__ z, const float* __restrict__ emb,
               const float* __restrict__ e2, int* __restrict__ idx,
               float* __restrict__ counts, int N)
{
    __shared__ float Es[256 * 64];        // 64KB
    __shared__ float bestS[4][64];
    __shared__ int   biS[4][64];
    const int tid = threadIdx.x;
    const int pt  = tid & 63;
    const int wvq = tid >> 6;             // wave 0..3
    const int n   = blockIdx.x * 64 + pt;
    const bool act = n < N;

    float x[64];
    float x2 = 0.0f;
    if (act) {
        const float4* zp = reinterpret_cast<const float4*>(z + (size_t)n * 64);
#pragma unroll
        for (int i = 0; i < 16; ++i) {
            float4 v = zp[i];
            x[4 * i + 0] = v.x; x[4 * i + 1] = v.y;
            x[4 * i + 2] = v.z; x[4 * i + 3] = v.w;
        }
#pragma unroll
        for (int d = 0; d < 64; ++d) x2 = fmaf(x[d], x[d], x2);
    }

    float best = 3.4e38f;
    int   bi   = 0;
    for (int pass = 0; pass < 2; ++pass) {
        __syncthreads();
        const float4* ep  = reinterpret_cast<const float4*>(emb + (size_t)pass * 16384);
        float4*       esp = reinterpret_cast<float4*>(Es);
#pragma unroll
        for (int i = 0; i < 16; ++i) esp[tid + 256 * i] = ep[tid + 256 * i];
        __syncthreads();
        const int c = pass * 4 + wvq;     // this wave's chunk
        for (int r = 0; r < 64; ++r) {
            const float4* er = reinterpret_cast<const float4*>(&Es[((size_t)wvq * 64 + r) * 64]);
            float dot = 0.0f;
#pragma unroll
            for (int i = 0; i < 16; ++i) {
                float4 e4 = er[i];
                dot = fmaf(x[4 * i + 0], e4.x, dot);
                dot = fmaf(x[4 * i + 1], e4.y, dot);
                dot = fmaf(x[4 * i + 2], e4.z, dot);
                dot = fmaf(x[4 * i + 3], e4.w, dot);
            }
            float dist = (e2[c * 64 + r] + x2) - 2.0f * dot;  // reference op order
            if (dist < best) { best = dist; bi = c * 64 + r; }
        }
    }
    bestS[wvq][pt] = best;
    biS[wvq][pt]   = bi;
    __syncthreads();
    if (wvq == 0 && act) {
        float bd = bestS[0][pt];
        int   bx = biS[0][pt];
#pragma unroll
        for (int g = 1; g < 4; ++g) {
            float d = bestS[g][pt];
            int   i2 = biS[g][pt];
            if (d < bd || (d == bd && i2 < bx)) { bd = d; bx = i2; }
        }
        idx[n] = bx;
        atomicAdd(&counts[bx], 1.0f);
    }
}

__global__ __launch_bounds__(256)
void vq_quant_loss(const float* __restrict__ z, const float* __restrict__ emb,
                   const int* __restrict__ idx, float* __restrict__ qout,
                   double* __restrict__ loss_sum, int Ntot)
{
    int g = blockIdx.x * 256 + threadIdx.x;
    float d2 = 0.0f;
    if (g < Ntot) {
        int n = g >> 6;
        int d = g & 63;
        float q  = emb[(size_t)idx[n] * 64 + d];
        float zv = z[g];
        qout[g] = zv + (q - zv);
        float diff = zv - q;
        d2 = diff * diff;
    }
#pragma unroll
    for (int o = 32; o > 0; o >>= 1) d2 += __shfl_down(d2, o);
    __shared__ float wsum[4];
    if ((threadIdx.x & 63) == 0) wsum[threadIdx.x >> 6] = d2;
    __syncthreads();
    if (threadIdx.x == 0)
        atomicAdd(loss_sum, (double)(wsum[0] + wsum[1] + wsum[2] + wsum[3]));
}

__global__ __launch_bounds__(512)
void vq_finalize(const float* __restrict__ counts, const double* __restrict__ loss_sum,
                 float* __restrict__ out, int Ntot, int Npts)
{
    int t = threadIdx.x;
    float c   = counts[t];
    float avg = c / (float)Npts;
    float term = avg * logf(avg + 1e-10f);
#pragma unroll
    for (int o = 32; o > 0; o >>= 1) term += __shfl_down(term, o);
    __shared__ float wsum[8];
    if ((t & 63) == 0) wsum[t >> 6] = term;
    __syncthreads();
    if (t == 0) {
        float s = 0.0f;
        for (int i = 0; i < 8; ++i) s += wsum[i];
        out[Ntot]     = 0.25f * (float)(loss_sum[0] / (double)Ntot);
        out[Ntot + 1] = expf(-s);
    }
}

// ================================ launcher ==================================
extern "C" void kernel_launch(void* const* d_in, const int* in_sizes, int n_in,
                              void* d_out, int out_size, void* d_ws, size_t ws_size,
                              hipStream_t stream)
{
    const float* mels     = (const float*)d_in[0];
    const float* w1       = (const float*)d_in[1];
    const float* w2       = (const float*)d_in[2];
    const float* w3       = (const float*)d_in[3];
    const float* w4       = (const float*)d_in[4];
    const float* w5       = (const float*)d_in[5];
    const float* w6       = (const float*)d_in[6];
    const float* b6       = (const float*)d_in[7];
    const float* bn_gamma = (const float*)d_in[8];
    const float* bn_beta  = (const float*)d_in[9];
    const float* bn_mean  = (const float*)d_in[10];
    const float* bn_var   = (const float*)d_in[11];
    const float* emb      = (const float*)d_in[12];

    constexpr int B = 32, C = 768, D = 64, T2 = 511;

    // Activations as H/L u16 planes [b][1024][768] (50,331,648 B each).
    char* ws = (char*)d_ws;
    constexpr size_t ACT = (size_t)32 * 1024 * 768;            // halfs per plane
    unsigned short* P1H = (unsigned short*)ws;
    unsigned short* P1L = P1H + ACT;
    unsigned short* P2H = (unsigned short*)(ws + 100663296);
    unsigned short* P2L = P2H + ACT;
    unsigned short* WHp = (unsigned short*)(ws + 201326592);   // 4,718,592 B (max KW=4)
    unsigned short* WLp = WHp + (size_t)4 * 768 * 768;         // 4,718,592 B
    size_t misc  = 201326592 + 9437184;
    float*  counts = (float*)(ws + misc);              // 2048 B
    double* lossp  = (double*)(ws + misc + 2048);      // 8 B (+pad)
    float*  e2p    = (float*)(ws + misc + 2048 + 64);  // 2048 B
    int*    idx    = (int*)(ws + misc + 2048 + 64 + 2048);  // 65,408 B

    unsigned short* MH = P2H;                          // mels planes (dead before conv2 out)
    unsigned short* ML = P2L;
    float* bufA = (float*)ws;                          // conv5 fp32 out (P1 dead)
    float* z    = (float*)(ws + 100663296);            // conv6 out (P2 dead)

    hipMemsetAsync(ws + misc, 0, 2048 + 64, stream);   // counts + loss

    vq_e2<<<dim3(2), 256, 0, stream>>>(emb, e2p);
    prep_mels<<<dim3((32 * 1032 * 96 + 255) / 256), 256, 0, stream>>>(mels, MH, ML);

    // conv1: Cin 80 (pad 96), KW 3, S1 P0, in MH/ML[1032][96] -> x1 = P1 [1024][768]
    prep_w<<<dim3((3 * 768 * 96 + 255) / 256), 256, 0, stream>>>(w1, WHp, WLp, 80, 3, 96);
    conv_mfma<3, 1, 0, 96, 1032, 1032, 1022, 1024, 0><<<dim3(6, 8, B), 512, 0, stream>>>(
        MH, ML, WHp, WLp, bn_gamma + 0 * C, bn_beta + 0 * C, bn_mean + 0 * C, bn_var + 0 * C,
        P1H, P1L, nullptr);
    // conv2: x1(P1) -> x2(P2)
    prep_w<<<dim3((3 * 768 * 768 + 255) / 256), 256, 0, stream>>>(w2, WHp, WLp, 768, 3, 768);
    conv_mfma<3, 1, 1, 768, 1022, 1024, 1022, 1024, 0><<<dim3(6, 8, B), 512, 0, stream>>>(
        P1H, P1L, WHp, WLp, bn_gamma + 1 * C, bn_beta + 1 * C, bn_mean + 1 * C, bn_var + 1 * C,
        P2H, P2L, nullptr);
    // conv3: stride 2, KW 4: x2(P2) -> x3(P1, stride 512)
    prep_w<<<dim3((4 * 768 * 768 + 255) / 256), 256, 0, stream>>>(w3, WHp, WLp, 768, 4, 768);
    conv_mfma<4, 2, 1, 768, 1022, 1024, 511, 512, 0><<<dim3(6, 4, B), 512, 0, stream>>>(
        P2H, P2L, WHp, WLp, bn_gamma + 2 * C, bn_beta + 2 * C, bn_mean + 2 * C, bn_var + 2 * C,
        P1H, P1L, nullptr);
    // conv4: x3(P1) -> x4(P2)
    prep_w<<<dim3((3 * 768 * 768 + 255) / 256), 256, 0, stream>>>(w4, WHp, WLp, 768, 3, 768);
    conv_mfma<3, 1, 1, 768, 511, 512, 511, 512, 0><<<dim3(6, 4, B), 512, 0, stream>>>(
        P1H, P1L, WHp, WLp, bn_gamma + 3 * C, bn_beta + 3 * C, bn_mean + 3 * C, bn_var + 3 * C,
        P2H, P2L, nullptr);
    // conv5: x4(P2) -> bufA fp32 [768][511] (EPI=1)
    prep_w<<<dim3((3 * 768 * 768 + 255) / 256), 256, 0, stream>>>(w5, WHp, WLp, 768, 3, 768);
    conv_mfma<3, 1, 1, 768, 511, 512, 511, 511, 1><<<dim3(6, 4, B), 512, 0, stream>>>(
        P2H, P2L, WHp, WLp, bn_gamma + 4 * C, bn_beta + 4 * C, bn_mean + 4 * C, bn_var + 4 * C,
        nullptr, nullptr, bufA);

    conv1x1_bias_T<<<dim3(1, 8, B), 256, 0, stream>>>(bufA, w6, b6, z, C, T2);

    const int Npts = B * T2;
    const int Ntot = Npts * D;
    vq_argmin<<<dim3((Npts + 63) / 64), 256, 0, stream>>>(z, emb, e2p, idx, counts, Npts);
    vq_quant_loss<<<dim3(Ntot / 256), 256, 0, stream>>>(z, emb, idx, (float*)d_out, lossp, Ntot);
    vq_finalize<<<dim3(1), 512, 0, stream>>>(counts, lossp, (float*)d_out, Ntot, Npts);
}